// Round 6
// baseline (232.880 us; speedup 1.0000x reference)
//
#include <hip/hip_runtime.h>
#include <hip/hip_cooperative_groups.h>
#include <math.h>

namespace cg = cooperative_groups;

#define TS 4
#define SDIM 128
#define PIX (SDIM * SDIM)
#define TEXW 512
#define TEXH 512
#define EPS 1e-9f
#define NCHUNK 16
#define NTILE 64   // 8x8 tiles of 16x16 pixels
#define NBLOCK (NTILE * NCHUNK)  // 1024 cooperative blocks
#define MAXCF 192
#define BBOX_MARGIN 1e-3f

__device__ __forceinline__ unsigned int enc_depth(float d) {
    unsigned int u = __float_as_uint(d);
    return (u & 0x80000000u) ? ~u : (u | 0x80000000u);
}

__global__ __launch_bounds__(256, 4) void fused_kernel(
    const float* __restrict__ verts, const int* __restrict__ faces,
    const void* __restrict__ azi_p, const void* __restrict__ ele_p,
    const float* __restrict__ img, const float* __restrict__ grid,
    float4* __restrict__ fd, unsigned long long* __restrict__ zbuf,
    float* __restrict__ out, int F, int chunkFaces) {
#pragma clang fp contract(off)
    cg::grid_group gg = cg::this_grid();

    // ---------------- Phase 1: face setup + zbuf init -----------------------
    {
        int t = blockIdx.x * 256 + threadIdx.x;
        if (t < F) {
            int f = t;
            // azi/ele are 1-element arrays; decode int-vs-float by bits.
            int ai = *(const int*)azi_p;
            float az = (ai > -360000 && ai < 360000) ? (float)ai
                                                     : *(const float*)azi_p;
            int ei = *(const int*)ele_p;
            float el = (ei > -360000 && ei < 360000) ? (float)ei
                                                     : *(const float*)ele_p;
            float a = az * (float)(M_PI / 180.0);
            float e = el * (float)(M_PI / 180.0);
            float ca = cosf(a), sa = sinf(a);
            float ce = cosf(e), se = sinf(e);
            float eye[3];
            eye[0] = 2.732f * (ce * sa);
            eye[1] = 2.732f * se;
            eye[2] = 2.732f * ((-ce) * ca);
            float nrm =
                sqrtf(eye[0] * eye[0] + eye[1] * eye[1] + eye[2] * eye[2]);
            float zv[3] = { (-eye[0]) / nrm, (-eye[1]) / nrm,
                            (-eye[2]) / nrm };
            // x = cross(up, z), up=(0,1,0); y = cross(z, x); both normalized
            float cx0 = 1.0f * zv[2] - 0.0f * zv[1];
            float cx1 = 0.0f * zv[0] - 0.0f * zv[2];
            float cx2 = 0.0f * zv[1] - 1.0f * zv[0];
            float xn = sqrtf(cx0 * cx0 + cx1 * cx1 + cx2 * cx2);
            float xv[3] = { cx0 / xn, cx1 / xn, cx2 / xn };
            float cy0 = zv[1] * xv[2] - zv[2] * xv[1];
            float cy1 = zv[2] * xv[0] - zv[0] * xv[2];
            float cy2 = zv[0] * xv[1] - zv[1] * xv[0];
            float yn = sqrtf(cy0 * cy0 + cy1 * cy1 + cy2 * cy2);
            float yv[3] = { cy0 / yn, cy1 / yn, cy2 / yn };

            float q[3][3];
            for (int k = 0; k < 3; ++k) {
                int vi = faces[f * 3 + k];
                float d0 = verts[vi * 3 + 0] - eye[0];
                float d1 = verts[vi * 3 + 1] - eye[1];
                float d2 = verts[vi * 3 + 2] - eye[2];
                q[k][0] = d0 * xv[0] + d1 * xv[1] + d2 * xv[2];
                q[k][1] = d0 * yv[0] + d1 * yv[1] + d2 * yv[2];
                q[k][2] = d0 * zv[0] + d1 * zv[1] + d2 * zv[2];
            }
            float e1x = q[1][0] - q[0][0], e1y = q[1][1] - q[0][1];
            float e2x = q[2][0] - q[0][0], e2y = q[2][1] - q[0][1];
            float det = e1x * e2y - e1y * e2x;
            bool valid = fabsf(det) > EPS;
            float inv = 1.0f / (valid ? det : 1.0f);
            // invalid det -> z=inf -> depth inf/NaN -> excluded by < INFINITY
            float z0 = valid ? q[0][2] : INFINITY;
            float z1 = valid ? q[1][2] : INFINITY;
            float z2 = valid ? q[2][2] : INFINITY;
            fd[f * 3 + 0] = make_float4(q[0][0], q[0][1], e1x, e1y);
            fd[f * 3 + 1] = make_float4(e2x, e2y, inv, 0.0f);
            fd[f * 3 + 2] = make_float4(z0, z1, z2, 0.0f);
        } else if (t < F + PIX) {
            zbuf[t - F] = ~0ull;
        }
    }
    gg.sync();

    // ---------------- Phase 2: tiled raster (bbox cull + LDS compaction) ----
    {
        __shared__ float4 sA[MAXCF];  // p0x p0y e1x e1y
        __shared__ float4 sB[MAXCF];  // e2x e2y inv fid(bits)
        __shared__ float4 sZ[MAXCF];  // z0 z1 z2 -
        __shared__ int cnt;
        if (threadIdx.x == 0) cnt = 0;
        __syncthreads();

        int tile = blockIdx.x & (NTILE - 1);
        int chunk = blockIdx.x >> 6;
        int tileX = tile & 7, tileY = tile >> 3;
        int f0 = chunk * chunkFaces;
        float xlo = (tileX * 16 + 0.5f) / 64.0f - 1.0f - BBOX_MARGIN;
        float xhi = (tileX * 16 + 15.5f) / 64.0f - 1.0f + BBOX_MARGIN;
        float yhi = 1.0f - (tileY * 16 + 0.5f) / 64.0f + BBOX_MARGIN;
        float ylo = 1.0f - (tileY * 16 + 15.5f) / 64.0f - BBOX_MARGIN;

        for (int k = threadIdx.x; k < chunkFaces; k += 256) {
            int f = f0 + k;
            if (f < F) {
                float4 A = fd[f * 3 + 0];
                float4 B = fd[f * 3 + 1];
                float4 C = fd[f * 3 + 2];
                float p1x = A.x + A.z, p1y = A.y + A.w;
                float p2x = A.x + B.x, p2y = A.y + B.y;
                float bxmin = fminf(A.x, fminf(p1x, p2x));
                float bxmax = fmaxf(A.x, fmaxf(p1x, p2x));
                float bymin = fminf(A.y, fminf(p1y, p2y));
                float bymax = fmaxf(A.y, fmaxf(p1y, p2y));
                if (bxmin <= xhi && bxmax >= xlo && bymin <= yhi &&
                    bymax >= ylo) {
                    int pos = atomicAdd(&cnt, 1);
                    if (pos < MAXCF) {
                        B.w = __int_as_float(f);
                        sA[pos] = A;
                        sB[pos] = B;
                        sZ[pos] = C;
                    }
                }
            }
        }
        __syncthreads();
        int n = min(cnt, MAXCF);

        if (n > 0) {
            int j = tileX * 16 + (threadIdx.x & 15);
            int i = tileY * 16 + (threadIdx.x >> 4);
            float px = ((j + 0.5f) / 128.0f) * 2.0f - 1.0f;
            float py = 1.0f - ((i + 0.5f) / 128.0f) * 2.0f;
            float best = INFINITY;
            int bfid = 0x7fffffff;
            bool have = false;
            for (int s = 0; s < n; ++s) {
                float4 A = sA[s];
                float4 B = sB[s];
                float4 C = sZ[s];
                float dx = px - A.x, dy = py - A.y;
                float w1 = (dx * B.y - dy * B.x) * B.z;
                float w2 = (A.z * dy - A.w * dx) * B.z;
                float w0 = 1.0f - w1 - w2;
                bool inside = (w0 >= 0.0f) && (w1 >= 0.0f) && (w2 >= 0.0f);
                float depth = w0 * C.x + w1 * C.y + w2 * C.z;
                int fid = __float_as_int(B.w);
                // lexicographic (depth,fid): order-independent first-min
                if (inside && depth < INFINITY &&
                    (depth < best || (depth == best && fid < bfid))) {
                    best = depth;
                    bfid = fid;
                    have = true;
                }
            }
            if (have) {
                unsigned long long pack =
                    ((unsigned long long)enc_depth(best) << 32) |
                    (unsigned int)bfid;
                atomicMin(&zbuf[i * SDIM + j], pack);
            }
        }
    }
    gg.sync();

    // ---------------- Phase 3: shade (first 64 blocks) ----------------------
    if (blockIdx.x < PIX / 256) {
        int t = blockIdx.x * 256 + threadIdx.x;
        int i = t >> 7, j = t & 127;
        int o = i * SDIM + (SDIM - 1 - j);  // x-flip ([..., ::-1])
        unsigned long long pack = zbuf[t];
        if (pack == ~0ull) {  // no finite hit -> zeros (matches where(hit))
            out[0 * PIX + o] = 0.0f;
            out[1 * PIX + o] = 0.0f;
            out[2 * PIX + o] = 0.0f;
            return;  // after last sync: divergent exit is safe
        }
        int bfid = (int)(unsigned int)(pack & 0xffffffffu);
        // recompute barycentrics for winning face (bit-identical exprs)
        float4 A = fd[bfid * 3 + 0];
        float4 B = fd[bfid * 3 + 1];
        float px = ((j + 0.5f) / 128.0f) * 2.0f - 1.0f;
        float py = 1.0f - ((i + 0.5f) / 128.0f) * 2.0f;
        float dx = px - A.x, dy = py - A.y;
        float w1 = (dx * B.y - dy * B.x) * B.z;
        float w2 = (A.z * dy - A.w * dx) * B.z;
        float w0 = 1.0f - w1 - w2;
        int i0 = min(max((int)floorf(w0 * (float)TS), 0), TS - 1);
        int i1 = min(max((int)floorf(w1 * (float)TS), 0), TS - 1);
        int i2 = min(max((int)floorf(w2 * (float)TS), 0), TS - 1);
        int sidx = bfid * (TS * TS * TS) + i0 * 16 + i1 * 4 + i2;
        // on-demand bilinear sample (bit-identical to reference grid_sample)
        float gx = grid[2 * sidx], gy = grid[2 * sidx + 1];
        float x = (gx + 1.0f) * (TEXW * 0.5f) - 0.5f;
        float y = (gy + 1.0f) * (TEXH * 0.5f) - 0.5f;
        float x0f = floorf(x), y0f = floorf(y);
        float tx = x - x0f, ty = y - y0f;
        int x0 = (int)x0f, y0 = (int)y0f;
        float w00 = (1.0f - tx) * (1.0f - ty);
        float w10 = tx * (1.0f - ty);
        float w01 = (1.0f - tx) * ty;
        float w11 = tx * ty;
        bool vx0 = (x0 >= 0) && (x0 < TEXW);
        bool vx1 = (x0 + 1 >= 0) && (x0 + 1 < TEXW);
        bool vy0 = (y0 >= 0) && (y0 < TEXH);
        bool vy1 = (y0 + 1 >= 0) && (y0 + 1 < TEXH);
        int xc0 = min(max(x0, 0), TEXW - 1);
        int xc1 = min(max(x0 + 1, 0), TEXW - 1);
        int yc0 = min(max(y0, 0), TEXH - 1);
        int yc1 = min(max(y0 + 1, 0), TEXH - 1);
        float W00 = (vx0 && vy0) ? w00 : 0.0f;
        float W10 = (vx1 && vy0) ? w10 : 0.0f;
        float W01 = (vx0 && vy1) ? w01 : 0.0f;
        float W11 = (vx1 && vy1) ? w11 : 0.0f;
        for (int c = 0; c < 3; ++c) {
            const float* ic = img + c * (TEXH * TEXW);
            float acc = ic[yc0 * TEXW + xc0] * W00;
            acc = acc + ic[yc0 * TEXW + xc1] * W10;
            acc = acc + ic[yc1 * TEXW + xc0] * W01;
            acc = acc + ic[yc1 * TEXW + xc1] * W11;
            out[c * PIX + o] = acc;
        }
    }
}

extern "C" void kernel_launch(void* const* d_in, const int* in_sizes, int n_in,
                              void* d_out, int out_size, void* d_ws,
                              size_t ws_size, hipStream_t stream) {
    const float* verts = (const float*)d_in[0];
    const float* img = (const float*)d_in[1];
    const float* grid = (const float*)d_in[2];
    const int* faces = (const int*)d_in[3];
    const void* azi = d_in[4];
    const void* ele = d_in[5];
    float* out = (float*)d_out;

    int F = in_sizes[3] / 3;  // faces

    char* ws = (char*)d_ws;
    size_t off = 0;
    float4* fd = (float4*)(ws + off);
    off += ((size_t)F * 3 * 16 + 255) & ~(size_t)255;
    unsigned long long* zbuf = (unsigned long long*)(ws + off);

    int chunkFaces = (F + NCHUNK - 1) / NCHUNK;  // 125 for F=2000 (<= MAXCF)

    void* args[] = { (void*)&verts, (void*)&faces, (void*)&azi, (void*)&ele,
                     (void*)&img,   (void*)&grid,  (void*)&fd,  (void*)&zbuf,
                     (void*)&out,   (void*)&F,     (void*)&chunkFaces };
    hipLaunchCooperativeKernel((const void*)fused_kernel, dim3(NBLOCK),
                               dim3(256), args, 0, stream);
}

// Round 7
// 195.956 us; speedup vs baseline: 1.1884x; 1.1884x over previous
//
#include <hip/hip_runtime.h>
#include <math.h>

#define TS 4
#define SDIM 128
#define PIX (SDIM * SDIM)
#define TEXW 512
#define TEXH 512
#define EPS 1e-9f
#define NCHUNK 32
#define NTILE 64  // 8x8 tiles of 16x16 pixels
#define NRB (NTILE * NCHUNK)  // 2048 raster blocks
#define MAXCF 128
#define BBOX_MARGIN 1e-3f

// ---------------- Kernel 1: face setup + zbuf/done init ---------------------
__device__ inline void cross3(const float a[3], const float b[3], float o[3]) {
    o[0] = a[1] * b[2] - a[2] * b[1];
    o[1] = a[2] * b[0] - a[0] * b[2];
    o[2] = a[0] * b[1] - a[1] * b[0];
}

__global__ void setup_kernel(const float* __restrict__ verts,
                             const int* __restrict__ faces,
                             const void* __restrict__ azi_p,
                             const void* __restrict__ ele_p,
                             float4* __restrict__ fd,
                             unsigned long long* __restrict__ zbuf,
                             unsigned int* __restrict__ done,
                             int F, int faceBlocks) {
#pragma clang fp contract(off)
    if ((int)blockIdx.x >= faceBlocks) {
        int t = (blockIdx.x - faceBlocks) * 256 + threadIdx.x;
        if (t < PIX) zbuf[t] = ~0ull;
        if (t == 0) *done = 0u;  // ws re-poisoned 0xAA each iter: must zero
        return;
    }
    int f = blockIdx.x * 256 + threadIdx.x;
    if (f >= F) return;
    // azi/ele are 1-element arrays; decode int-vs-float by bit pattern.
    int ai = *(const int*)azi_p;
    float az = (ai > -360000 && ai < 360000) ? (float)ai : *(const float*)azi_p;
    int ei = *(const int*)ele_p;
    float el = (ei > -360000 && ei < 360000) ? (float)ei : *(const float*)ele_p;
    float a = az * (float)(M_PI / 180.0);
    float e = el * (float)(M_PI / 180.0);
    float ca = cosf(a), sa = sinf(a);
    float ce = cosf(e), se = sinf(e);
    float eye[3];
    eye[0] = 2.732f * (ce * sa);
    eye[1] = 2.732f * se;
    eye[2] = 2.732f * ((-ce) * ca);
    float nrm = sqrtf(eye[0] * eye[0] + eye[1] * eye[1] + eye[2] * eye[2]);
    float zv[3] = { (-eye[0]) / nrm, (-eye[1]) / nrm, (-eye[2]) / nrm };
    float up[3] = { 0.0f, 1.0f, 0.0f };
    float xv[3];
    cross3(up, zv, xv);
    float xn = sqrtf(xv[0] * xv[0] + xv[1] * xv[1] + xv[2] * xv[2]);
    xv[0] /= xn; xv[1] /= xn; xv[2] /= xn;
    float yv[3];
    cross3(zv, xv, yv);
    float yn = sqrtf(yv[0] * yv[0] + yv[1] * yv[1] + yv[2] * yv[2]);
    yv[0] /= yn; yv[1] /= yn; yv[2] /= yn;

    float q[3][3];
    for (int k = 0; k < 3; ++k) {
        int vi = faces[f * 3 + k];
        float d0 = verts[vi * 3 + 0] - eye[0];
        float d1 = verts[vi * 3 + 1] - eye[1];
        float d2 = verts[vi * 3 + 2] - eye[2];
        q[k][0] = d0 * xv[0] + d1 * xv[1] + d2 * xv[2];
        q[k][1] = d0 * yv[0] + d1 * yv[1] + d2 * yv[2];
        q[k][2] = d0 * zv[0] + d1 * zv[1] + d2 * zv[2];
    }
    float e1x = q[1][0] - q[0][0], e1y = q[1][1] - q[0][1];
    float e2x = q[2][0] - q[0][0], e2y = q[2][1] - q[0][1];
    float det = e1x * e2y - e1y * e2x;
    bool valid = fabsf(det) > EPS;
    float inv = 1.0f / (valid ? det : 1.0f);
    // invalid det -> z=inf so depth is inf/NaN -> never selected
    float z0 = valid ? q[0][2] : INFINITY;
    float z1 = valid ? q[1][2] : INFINITY;
    float z2 = valid ? q[2][2] : INFINITY;
    fd[f * 3 + 0] = make_float4(q[0][0], q[0][1], e1x, e1y);
    fd[f * 3 + 1] = make_float4(e2x, e2y, inv, 0.0f);
    fd[f * 3 + 2] = make_float4(z0, z1, z2, 0.0f);
}

// monotone float->uint encoding (works for any sign; NaN excluded by caller)
__device__ inline unsigned int enc_depth(float d) {
    unsigned int u = __float_as_uint(d);
    return (u & 0x80000000u) ? ~u : (u | 0x80000000u);
}

// ---------------- Kernel 2: raster + last-arrival shade ---------------------
// 2048 blocks: block b -> tile (b & 63), chunk (b >> 6). After raster, each
// block takes a ticket; the last 64 blocks shade one 256-pixel slice each.
// All inter-block communication is via device-scope atomics (zbuf, done).
__global__ void raster_shade_kernel(const float4* __restrict__ fd, int F,
                                    int chunkFaces,
                                    unsigned long long* __restrict__ zbuf,
                                    unsigned int* __restrict__ done,
                                    const float* __restrict__ img,
                                    const float* __restrict__ grid,
                                    float* __restrict__ out) {
#pragma clang fp contract(off)
    __shared__ float4 sA[MAXCF];  // p0x p0y e1x e1y
    __shared__ float4 sB[MAXCF];  // e2x e2y inv fid(bits)
    __shared__ float4 sZ[MAXCF];  // z0 z1 z2 -
    __shared__ int cnt;
    __shared__ unsigned int sticket;
    if (threadIdx.x == 0) cnt = 0;
    __syncthreads();

    int tile = blockIdx.x & (NTILE - 1);
    int chunk = blockIdx.x >> 6;
    int tileX = tile & 7, tileY = tile >> 3;
    int f0 = chunk * chunkFaces;
    // tile NDC bounds (pixel centers) with conservative margin
    float xlo = (tileX * 16 + 0.5f) / 64.0f - 1.0f - BBOX_MARGIN;
    float xhi = (tileX * 16 + 15.5f) / 64.0f - 1.0f + BBOX_MARGIN;
    float yhi = 1.0f - (tileY * 16 + 0.5f) / 64.0f + BBOX_MARGIN;
    float ylo = 1.0f - (tileY * 16 + 15.5f) / 64.0f - BBOX_MARGIN;

    int k = threadIdx.x;
    int f = f0 + k;
    if (k < chunkFaces && f < F) {
        float4 A = fd[f * 3 + 0];
        float4 B = fd[f * 3 + 1];
        float4 C = fd[f * 3 + 2];
        float p1x = A.x + A.z, p1y = A.y + A.w;
        float p2x = A.x + B.x, p2y = A.y + B.y;
        float bxmin = fminf(A.x, fminf(p1x, p2x));
        float bxmax = fmaxf(A.x, fmaxf(p1x, p2x));
        float bymin = fminf(A.y, fminf(p1y, p2y));
        float bymax = fmaxf(A.y, fmaxf(p1y, p2y));
        if (bxmin <= xhi && bxmax >= xlo && bymin <= yhi && bymax >= ylo) {
            int pos = atomicAdd(&cnt, 1);
            B.w = __int_as_float(f);
            sA[pos] = A;
            sB[pos] = B;
            sZ[pos] = C;
        }
    }
    __syncthreads();
    int n = cnt;

    if (n > 0) {
        int j = tileX * 16 + (threadIdx.x & 15);
        int i = tileY * 16 + (threadIdx.x >> 4);
        float px = ((j + 0.5f) / 128.0f) * 2.0f - 1.0f;
        float py = 1.0f - ((i + 0.5f) / 128.0f) * 2.0f;
        float best = INFINITY;
        int bfid = 0x7fffffff;
        bool have = false;
        for (int s = 0; s < n; ++s) {
            float4 A = sA[s];
            float4 B = sB[s];
            float4 C = sZ[s];
            float dx = px - A.x, dy = py - A.y;
            float w1 = (dx * B.y - dy * B.x) * B.z;
            float w2 = (A.z * dy - A.w * dx) * B.z;
            float w0 = 1.0f - w1 - w2;
            bool inside = (w0 >= 0.0f) && (w1 >= 0.0f) && (w2 >= 0.0f);
            float depth = w0 * C.x + w1 * C.y + w2 * C.z;
            int fid = __float_as_int(B.w);
            // lexicographic (depth, fid): order-independent == first-min
            if (inside && depth < INFINITY &&
                (depth < best || (depth == best && fid < bfid))) {
                best = depth;
                bfid = fid;
                have = true;
            }
        }
        if (have) {
            unsigned long long pack =
                ((unsigned long long)enc_depth(best) << 32) |
                (unsigned int)bfid;
            atomicMin(&zbuf[i * SDIM + j], pack);
        }
    }

    // ---- ticket: last 64 arriving blocks shade one slice each ----
    __threadfence();  // make this block's zbuf atomics globally visible
    if (threadIdx.x == 0) sticket = atomicAdd(done, 1u) + 1u;
    __syncthreads();
    unsigned int ticket = sticket;
    if (ticket <= NRB - (PIX / 256)) return;  // not a shade block
    int slice = (int)ticket - (NRB - (PIX / 256)) - 1;  // 0..63

    if (threadIdx.x == 0) {
        while (atomicAdd(done, 0u) < (unsigned int)NRB) { /* spin */ }
    }
    __syncthreads();
    __threadfence();

    int t = slice * 256 + threadIdx.x;
    int i = t >> 7, j = t & 127;
    int o = i * SDIM + (SDIM - 1 - j);  // x-flip ([..., ::-1])
    // atomic read of zbuf (min with max == load, device-scope)
    unsigned long long pack = atomicMin(&zbuf[t], ~0ull);
    if (pack == ~0ull) {  // no finite hit -> zeros (matches where(hit))
        out[0 * PIX + o] = 0.0f;
        out[1 * PIX + o] = 0.0f;
        out[2 * PIX + o] = 0.0f;
        return;
    }
    int bfid = (int)(unsigned int)(pack & 0xffffffffu);
    // recompute barycentrics for winning face (bit-identical exprs)
    float4 A = fd[bfid * 3 + 0];
    float4 B = fd[bfid * 3 + 1];
    float px = ((j + 0.5f) / 128.0f) * 2.0f - 1.0f;
    float py = 1.0f - ((i + 0.5f) / 128.0f) * 2.0f;
    float dx = px - A.x, dy = py - A.y;
    float w1 = (dx * B.y - dy * B.x) * B.z;
    float w2 = (A.z * dy - A.w * dx) * B.z;
    float w0 = 1.0f - w1 - w2;
    int i0 = min(max((int)floorf(w0 * (float)TS), 0), TS - 1);
    int i1 = min(max((int)floorf(w1 * (float)TS), 0), TS - 1);
    int i2 = min(max((int)floorf(w2 * (float)TS), 0), TS - 1);
    int sidx = bfid * (TS * TS * TS) + i0 * 16 + i1 * 4 + i2;
    // on-demand bilinear sample (bit-identical to reference grid_sample)
    float gx = grid[2 * sidx], gy = grid[2 * sidx + 1];
    float x = (gx + 1.0f) * (TEXW * 0.5f) - 0.5f;
    float y = (gy + 1.0f) * (TEXH * 0.5f) - 0.5f;
    float x0f = floorf(x), y0f = floorf(y);
    float tx = x - x0f, ty = y - y0f;
    int x0 = (int)x0f, y0 = (int)y0f;
    float w00 = (1.0f - tx) * (1.0f - ty);
    float w10 = tx * (1.0f - ty);
    float w01 = (1.0f - tx) * ty;
    float w11 = tx * ty;
    bool vx0 = (x0 >= 0) && (x0 < TEXW);
    bool vx1 = (x0 + 1 >= 0) && (x0 + 1 < TEXW);
    bool vy0 = (y0 >= 0) && (y0 < TEXH);
    bool vy1 = (y0 + 1 >= 0) && (y0 + 1 < TEXH);
    int xc0 = min(max(x0, 0), TEXW - 1);
    int xc1 = min(max(x0 + 1, 0), TEXW - 1);
    int yc0 = min(max(y0, 0), TEXH - 1);
    int yc1 = min(max(y0 + 1, 0), TEXH - 1);
    float W00 = (vx0 && vy0) ? w00 : 0.0f;
    float W10 = (vx1 && vy0) ? w10 : 0.0f;
    float W01 = (vx0 && vy1) ? w01 : 0.0f;
    float W11 = (vx1 && vy1) ? w11 : 0.0f;
    for (int c = 0; c < 3; ++c) {
        const float* ic = img + c * (TEXH * TEXW);
        float acc = ic[yc0 * TEXW + xc0] * W00;
        acc = acc + ic[yc0 * TEXW + xc1] * W10;
        acc = acc + ic[yc1 * TEXW + xc0] * W01;
        acc = acc + ic[yc1 * TEXW + xc1] * W11;
        out[c * PIX + o] = acc;
    }
}

extern "C" void kernel_launch(void* const* d_in, const int* in_sizes, int n_in,
                              void* d_out, int out_size, void* d_ws,
                              size_t ws_size, hipStream_t stream) {
    const float* verts = (const float*)d_in[0];
    const float* img = (const float*)d_in[1];
    const float* grid = (const float*)d_in[2];
    const int* faces = (const int*)d_in[3];
    const void* azi = d_in[4];
    const void* ele = d_in[5];
    float* out = (float*)d_out;

    int F = in_sizes[3] / 3;  // faces

    char* ws = (char*)d_ws;
    size_t off = 0;
    float4* fd = (float4*)(ws + off);
    off += ((size_t)F * 3 * 16 + 255) & ~(size_t)255;
    unsigned long long* zbuf = (unsigned long long*)(ws + off);
    off += (size_t)PIX * 8;
    unsigned int* done = (unsigned int*)(ws + off);

    int faceBlocks = (F + 255) / 256;
    int zBlocks = (PIX + 255) / 256;
    int chunkFaces = (F + NCHUNK - 1) / NCHUNK;  // 63 for F=2000 (<= MAXCF)

    setup_kernel<<<faceBlocks + zBlocks, 256, 0, stream>>>(
        verts, faces, azi, ele, fd, zbuf, done, F, faceBlocks);
    raster_shade_kernel<<<NRB, 256, 0, stream>>>(fd, F, chunkFaces, zbuf,
                                                 done, img, grid, out);
}

// Round 8
// 86.127 us; speedup vs baseline: 2.7039x; 2.2752x over previous
//
#include <hip/hip_runtime.h>
#include <math.h>

#define TS 4
#define SDIM 128
#define PIX (SDIM * SDIM)
#define TEXW 512
#define TEXH 512
#define EPS 1e-9f
#define NCHUNK 32
#define NTILE 64  // 8x8 tiles of 16x16 pixels
#define MAXCF 128
#define BBOX_MARGIN 1e-3f

// ---------------- Kernel 1: face setup + zbuf init --------------------------
__device__ inline void cross3(const float a[3], const float b[3], float o[3]) {
    o[0] = a[1] * b[2] - a[2] * b[1];
    o[1] = a[2] * b[0] - a[0] * b[2];
    o[2] = a[0] * b[1] - a[1] * b[0];
}

__global__ void setup_kernel(const float* __restrict__ verts,
                             const int* __restrict__ faces,
                             const void* __restrict__ azi_p,
                             const void* __restrict__ ele_p,
                             float4* __restrict__ fd,
                             unsigned long long* __restrict__ zbuf,
                             int F, int faceBlocks) {
#pragma clang fp contract(off)
    if ((int)blockIdx.x >= faceBlocks) {
        int t = (blockIdx.x - faceBlocks) * 256 + threadIdx.x;
        if (t < PIX) zbuf[t] = ~0ull;
        return;
    }
    int f = blockIdx.x * 256 + threadIdx.x;
    if (f >= F) return;
    // azi/ele are 1-element arrays; decode int-vs-float by bit pattern.
    int ai = *(const int*)azi_p;
    float az = (ai > -360000 && ai < 360000) ? (float)ai : *(const float*)azi_p;
    int ei = *(const int*)ele_p;
    float el = (ei > -360000 && ei < 360000) ? (float)ei : *(const float*)ele_p;
    float a = az * (float)(M_PI / 180.0);
    float e = el * (float)(M_PI / 180.0);
    float ca = cosf(a), sa = sinf(a);
    float ce = cosf(e), se = sinf(e);
    float eye[3];
    eye[0] = 2.732f * (ce * sa);
    eye[1] = 2.732f * se;
    eye[2] = 2.732f * ((-ce) * ca);
    float nrm = sqrtf(eye[0] * eye[0] + eye[1] * eye[1] + eye[2] * eye[2]);
    float zv[3] = { (-eye[0]) / nrm, (-eye[1]) / nrm, (-eye[2]) / nrm };
    float up[3] = { 0.0f, 1.0f, 0.0f };
    float xv[3];
    cross3(up, zv, xv);
    float xn = sqrtf(xv[0] * xv[0] + xv[1] * xv[1] + xv[2] * xv[2]);
    xv[0] /= xn; xv[1] /= xn; xv[2] /= xn;
    float yv[3];
    cross3(zv, xv, yv);
    float yn = sqrtf(yv[0] * yv[0] + yv[1] * yv[1] + yv[2] * yv[2]);
    yv[0] /= yn; yv[1] /= yn; yv[2] /= yn;

    float q[3][3];
    for (int k = 0; k < 3; ++k) {
        int vi = faces[f * 3 + k];
        float d0 = verts[vi * 3 + 0] - eye[0];
        float d1 = verts[vi * 3 + 1] - eye[1];
        float d2 = verts[vi * 3 + 2] - eye[2];
        q[k][0] = d0 * xv[0] + d1 * xv[1] + d2 * xv[2];
        q[k][1] = d0 * yv[0] + d1 * yv[1] + d2 * yv[2];
        q[k][2] = d0 * zv[0] + d1 * zv[1] + d2 * zv[2];
    }
    float e1x = q[1][0] - q[0][0], e1y = q[1][1] - q[0][1];
    float e2x = q[2][0] - q[0][0], e2y = q[2][1] - q[0][1];
    float det = e1x * e2y - e1y * e2x;
    bool valid = fabsf(det) > EPS;
    float inv = 1.0f / (valid ? det : 1.0f);
    // invalid det -> z=inf so depth is inf/NaN -> never selected
    float z0 = valid ? q[0][2] : INFINITY;
    float z1 = valid ? q[1][2] : INFINITY;
    float z2 = valid ? q[2][2] : INFINITY;
    fd[f * 3 + 0] = make_float4(q[0][0], q[0][1], e1x, e1y);
    fd[f * 3 + 1] = make_float4(e2x, e2y, inv, 0.0f);
    fd[f * 3 + 2] = make_float4(z0, z1, z2, 0.0f);
}

// monotone float->uint encoding (works for any sign; NaN excluded by caller)
__device__ inline unsigned int enc_depth(float d) {
    unsigned int u = __float_as_uint(d);
    return (u & 0x80000000u) ? ~u : (u | 0x80000000u);
}

// ---------------- Kernel 2: tiled raster: bbox cull + LDS compaction --------
// grid = (NTILE, NCHUNK); block = 256 = one 16x16-pixel tile x one face chunk
__global__ void raster_kernel(const float4* __restrict__ fd, int F,
                              int chunkFaces,
                              unsigned long long* __restrict__ zbuf) {
#pragma clang fp contract(off)
    __shared__ float4 sA[MAXCF];  // p0x p0y e1x e1y
    __shared__ float4 sB[MAXCF];  // e2x e2y inv fid(bits)
    __shared__ float4 sZ[MAXCF];  // z0 z1 z2 -
    __shared__ int cnt;
    if (threadIdx.x == 0) cnt = 0;
    __syncthreads();

    int tileX = blockIdx.x & 7, tileY = blockIdx.x >> 3;
    int f0 = blockIdx.y * chunkFaces;
    // tile NDC bounds (pixel centers) with conservative margin
    float xlo = (tileX * 16 + 0.5f) / 64.0f - 1.0f - BBOX_MARGIN;
    float xhi = (tileX * 16 + 15.5f) / 64.0f - 1.0f + BBOX_MARGIN;
    float yhi = 1.0f - (tileY * 16 + 0.5f) / 64.0f + BBOX_MARGIN;
    float ylo = 1.0f - (tileY * 16 + 15.5f) / 64.0f - BBOX_MARGIN;

    int k = threadIdx.x;
    int f = f0 + k;
    if (k < chunkFaces && f < F) {
        float4 A = fd[f * 3 + 0];
        float4 B = fd[f * 3 + 1];
        float4 C = fd[f * 3 + 2];
        float p1x = A.x + A.z, p1y = A.y + A.w;
        float p2x = A.x + B.x, p2y = A.y + B.y;
        float bxmin = fminf(A.x, fminf(p1x, p2x));
        float bxmax = fmaxf(A.x, fmaxf(p1x, p2x));
        float bymin = fminf(A.y, fminf(p1y, p2y));
        float bymax = fmaxf(A.y, fmaxf(p1y, p2y));
        if (bxmin <= xhi && bxmax >= xlo && bymin <= yhi && bymax >= ylo) {
            int pos = atomicAdd(&cnt, 1);
            B.w = __int_as_float(f);
            sA[pos] = A;
            sB[pos] = B;
            sZ[pos] = C;
        }
    }
    __syncthreads();
    int n = cnt;
    if (n == 0) return;

    int j = tileX * 16 + (threadIdx.x & 15);
    int i = tileY * 16 + (threadIdx.x >> 4);
    float px = ((j + 0.5f) / 128.0f) * 2.0f - 1.0f;
    float py = 1.0f - ((i + 0.5f) / 128.0f) * 2.0f;
    float best = INFINITY;
    int bfid = 0x7fffffff;
    bool have = false;
    for (int s = 0; s < n; ++s) {
        float4 A = sA[s];
        float4 B = sB[s];
        float4 C = sZ[s];
        float dx = px - A.x, dy = py - A.y;
        float w1 = (dx * B.y - dy * B.x) * B.z;
        float w2 = (A.z * dy - A.w * dx) * B.z;
        float w0 = 1.0f - w1 - w2;
        bool inside = (w0 >= 0.0f) && (w1 >= 0.0f) && (w2 >= 0.0f);
        float depth = w0 * C.x + w1 * C.y + w2 * C.z;
        int fid = __float_as_int(B.w);
        // lexicographic (depth, fid): order-independent == first-min argmin
        if (inside && depth < INFINITY &&
            (depth < best || (depth == best && fid < bfid))) {
            best = depth;
            bfid = fid;
            have = true;
        }
    }
    if (have) {
        unsigned long long pack =
            ((unsigned long long)enc_depth(best) << 32) | (unsigned int)bfid;
        atomicMin(&zbuf[i * SDIM + j], pack);
    }
}

// ---------------- Kernel 3: shade (decode zbuf + on-demand bilinear) --------
__global__ void shade_kernel(const unsigned long long* __restrict__ zbuf,
                             const float4* __restrict__ fd,
                             const float* __restrict__ img,
                             const float* __restrict__ grid,
                             float* __restrict__ out) {
#pragma clang fp contract(off)
    int t = blockIdx.x * 256 + threadIdx.x;
    int i = t >> 7, j = t & 127;
    int o = i * SDIM + (SDIM - 1 - j);  // x-flip ([..., ::-1])
    unsigned long long pack = zbuf[t];
    if (pack == ~0ull) {  // no finite hit -> zeros (matches where(hit))
        out[0 * PIX + o] = 0.0f;
        out[1 * PIX + o] = 0.0f;
        out[2 * PIX + o] = 0.0f;
        return;
    }
    int bfid = (int)(unsigned int)(pack & 0xffffffffu);
    // recompute barycentrics for winning face (bit-identical exprs)
    float4 A = fd[bfid * 3 + 0];
    float4 B = fd[bfid * 3 + 1];
    float px = ((j + 0.5f) / 128.0f) * 2.0f - 1.0f;
    float py = 1.0f - ((i + 0.5f) / 128.0f) * 2.0f;
    float dx = px - A.x, dy = py - A.y;
    float w1 = (dx * B.y - dy * B.x) * B.z;
    float w2 = (A.z * dy - A.w * dx) * B.z;
    float w0 = 1.0f - w1 - w2;
    int i0 = min(max((int)floorf(w0 * (float)TS), 0), TS - 1);
    int i1 = min(max((int)floorf(w1 * (float)TS), 0), TS - 1);
    int i2 = min(max((int)floorf(w2 * (float)TS), 0), TS - 1);
    int sidx = bfid * (TS * TS * TS) + i0 * 16 + i1 * 4 + i2;
    // on-demand bilinear sample (bit-identical to reference grid_sample)
    float gx = grid[2 * sidx], gy = grid[2 * sidx + 1];
    float x = (gx + 1.0f) * (TEXW * 0.5f) - 0.5f;
    float y = (gy + 1.0f) * (TEXH * 0.5f) - 0.5f;
    float x0f = floorf(x), y0f = floorf(y);
    float tx = x - x0f, ty = y - y0f;
    int x0 = (int)x0f, y0 = (int)y0f;
    float w00 = (1.0f - tx) * (1.0f - ty);
    float w10 = tx * (1.0f - ty);
    float w01 = (1.0f - tx) * ty;
    float w11 = tx * ty;
    bool vx0 = (x0 >= 0) && (x0 < TEXW);
    bool vx1 = (x0 + 1 >= 0) && (x0 + 1 < TEXW);
    bool vy0 = (y0 >= 0) && (y0 < TEXH);
    bool vy1 = (y0 + 1 >= 0) && (y0 + 1 < TEXH);
    int xc0 = min(max(x0, 0), TEXW - 1);
    int xc1 = min(max(x0 + 1, 0), TEXW - 1);
    int yc0 = min(max(y0, 0), TEXH - 1);
    int yc1 = min(max(y0 + 1, 0), TEXH - 1);
    float W00 = (vx0 && vy0) ? w00 : 0.0f;
    float W10 = (vx1 && vy0) ? w10 : 0.0f;
    float W01 = (vx0 && vy1) ? w01 : 0.0f;
    float W11 = (vx1 && vy1) ? w11 : 0.0f;
    for (int c = 0; c < 3; ++c) {
        const float* ic = img + c * (TEXH * TEXW);
        float acc = ic[yc0 * TEXW + xc0] * W00;
        acc = acc + ic[yc0 * TEXW + xc1] * W10;
        acc = acc + ic[yc1 * TEXW + xc0] * W01;
        acc = acc + ic[yc1 * TEXW + xc1] * W11;
        out[c * PIX + o] = acc;
    }
}

extern "C" void kernel_launch(void* const* d_in, const int* in_sizes, int n_in,
                              void* d_out, int out_size, void* d_ws,
                              size_t ws_size, hipStream_t stream) {
    const float* verts = (const float*)d_in[0];
    const float* img = (const float*)d_in[1];
    const float* grid = (const float*)d_in[2];
    const int* faces = (const int*)d_in[3];
    const void* azi = d_in[4];
    const void* ele = d_in[5];
    float* out = (float*)d_out;

    int F = in_sizes[3] / 3;  // faces

    char* ws = (char*)d_ws;
    size_t off = 0;
    float4* fd = (float4*)(ws + off);
    off += ((size_t)F * 3 * 16 + 255) & ~(size_t)255;
    unsigned long long* zbuf = (unsigned long long*)(ws + off);

    int faceBlocks = (F + 255) / 256;
    int zBlocks = (PIX + 255) / 256;
    int chunkFaces = (F + NCHUNK - 1) / NCHUNK;  // 63 for F=2000 (<= MAXCF)

    setup_kernel<<<faceBlocks + zBlocks, 256, 0, stream>>>(
        verts, faces, azi, ele, fd, zbuf, F, faceBlocks);
    raster_kernel<<<dim3(NTILE, NCHUNK), 256, 0, stream>>>(fd, F, chunkFaces,
                                                           zbuf);
    shade_kernel<<<PIX / 256, 256, 0, stream>>>(zbuf, fd, img, grid, out);
}